// Round 3
// baseline (1257.760 us; speedup 1.0000x reference)
//
#include <hip/hip_runtime.h>

#define IN_DIM   512
#define OUT_DIM  256
#define N_MID    1280
#define N_NODES  1792
#define BATCH    16384
#define ROWS     16
#define NT       256
#define XPAD     520      // fallback kernel only
#define RS       40       // res_lds row stride (bf16 elems): 80B, 16B-aligned, 2-way banks

// max-geometry for workspace sizing (Mc up to 1280 -> Mpad up to 1280)
#define MPAD_MAX  1280
#define TPM_MAX   (MPAD_MAX / 16)          // 80 col-tiles
#define KST_MAX   ((IN_DIM + MPAD_MAX)/32) // 56 k-steps
#define NCH_MAX   (MPAD_MAX / 32)          // 40 chunks

// ---- workspace layout ----
#define EW2_ELEMS ((size_t)KST_MAX * TPM_MAX * 64 * 8)     // bf16 elems
#define EW2_BYTES (EW2_ELEMS * 2)                          // 4,587,520
#define TRI_OFF   EW2_BYTES
#define TRI_BYTES ((size_t)NCH_MAX * 32 * 32 * 4)          // 163,840
#define HDR_OFF   (TRI_OFF + TRI_BYTES)
#define CMAP_OFF  (HDR_OFF + 32)
#define OCOL_OFF  (CMAP_OFF + N_MID * 4)
#define BIASC_OFF (OCOL_OFF + N_MID * 4)
#define WS_NEED   (BIASC_OFF + N_MID * 4)

typedef __attribute__((ext_vector_type(8))) short  bfrag;
typedef __attribute__((ext_vector_type(4))) float  ffrag;

__device__ __forceinline__ unsigned short f2bf(float f) {
    unsigned int u = __float_as_uint(f);
    u += 0x7FFFu + ((u >> 16) & 1u);       // RNE
    return (unsigned short)(u >> 16);
}

// ============================================================
// Setup A: compact existing columns (1 wave).
// hdr = {Mc, Mpad, ntw=Mpad/64, nch=Mpad/32, tpm=Mpad/16}
// ============================================================
__global__ void build_maps_kernel(const int* __restrict__ exist,
                                  const float* __restrict__ bias,
                                  int* __restrict__ hdr,
                                  int* __restrict__ cmap,
                                  int* __restrict__ ocol,
                                  float* __restrict__ biasc) {
    const int lane = threadIdx.x;   // 64
    int base = 0;
    for (int r = 0; r < N_MID / 64; ++r) {
        const int i = r * 64 + lane;
        const int e = exist[i];
        const unsigned long long m  = __ballot(e != 0);
        const unsigned long long lt = (lane == 0) ? 0ull : (~0ull >> (64 - lane));
        const int pos = base + __popcll(m & lt);
        if (e) {
            cmap[pos]  = i;
            ocol[pos]  = (i >= N_MID - OUT_DIM) ? (i - (N_MID - OUT_DIM)) : -1;
            biasc[pos] = bias[i];
        }
        base += __popcll(m);
    }
    for (int idx = base + lane; idx < N_MID; idx += 64) {
        cmap[idx] = 0; ocol[idx] = -1; biasc[idx] = 0.f;
    }
    if (lane == 0) {
        const int Mc   = base;
        const int Mpad = (Mc + 127) & ~127;    // ntw even (chunk never straddles a wave)
        hdr[0] = Mc; hdr[1] = Mpad; hdr[2] = Mpad / 64;
        hdr[3] = Mpad / 32; hdr[4] = Mpad / 16;
    }
}

// ============================================================
// Setup B: gather eff_w -> bf16 in MFMA B-fragment-major layout.
// ew2[((kstep*tpm + gt)*64 + lane)*8 + j] = W[s][c], bf16
//   s = kstep*32 + (lane>>4)*8 + j   (k index)
//   c = gt*16 + (lane&15)            (n index)
// kstep<16: phase-1 (input rows). kstep>=16: phase-2, s2 = s-512 compacted src;
// zero unless s2<c, both <Mc, and different chunk (same-chunk handled by tri).
// ============================================================
__global__ __launch_bounds__(NT)
void gather2_kernel(const float* __restrict__ w, const int* __restrict__ conn,
                    const int* __restrict__ hdr, const int* __restrict__ cmap,
                    unsigned short* __restrict__ ew2) {
    const int Mc = hdr[0], nch = hdr[3], tpm = hdr[4];
    const int tid  = blockIdx.x * NT + threadIdx.x;
    const int lane = tid & 63;
    const int gl   = tid >> 6;
    const int gt   = gl % tpm;
    const int kstep = gl / tpm;
    if (kstep >= 16 + nch) return;
    const int c = gt * 16 + (lane & 15);
    const int k0 = kstep * 32 + ((lane >> 4) << 3);
    unsigned short v[8];
#pragma unroll
    for (int j = 0; j < 8; ++j) {
        const int s = k0 + j;
        float val = 0.f;
        if (c < Mc) {
            const int cc = cmap[c];
            if (s < IN_DIM) {
                const size_t o = (size_t)s * N_MID + cc;
                val = w[o] * (float)conn[o];
            } else {
                const int s2 = s - IN_DIM;
                if (s2 < Mc && s2 < c && (s2 >> 5) != (c >> 5)) {
                    const size_t o = (size_t)(IN_DIM + cmap[s2]) * N_MID + cc;
                    val = w[o] * (float)conn[o];
                }
            }
        }
        v[j] = f2bf(val);
    }
    *(uint4*)&ew2[((size_t)(kstep * tpm + gt) * 64 + lane) * 8] = *(uint4*)v;
}

// ============================================================
// Setup C: in-chunk triangle weights, fp32. tri[j][sl][cl], nonzero iff sl<cl.
// ============================================================
__global__ __launch_bounds__(NT)
void gather_tri_kernel(const float* __restrict__ w, const int* __restrict__ conn,
                       const int* __restrict__ hdr, const int* __restrict__ cmap,
                       float* __restrict__ tri) {
    const int Mc = hdr[0], nch = hdr[3];
    const int idx = blockIdx.x * NT + threadIdx.x;
    if (idx >= NCH_MAX * 1024) return;
    const int j  = idx >> 10;
    if (j >= nch) return;
    const int sl = (idx >> 5) & 31;
    const int cl = idx & 31;
    const int s = j * 32 + sl, c = j * 32 + cl;
    float v = 0.f;
    if (sl < cl && c < Mc) {
        const size_t o = (size_t)(IN_DIM + cmap[s]) * N_MID + cmap[c];
        v = w[o] * (float)conn[o];
    }
    tri[idx] = v;
}

// ============================================================
// Main kernel. Wave w owns col-tiles [w*ntw, (w+1)*ntw).
// Phase 1: bf16 MFMA GEMM [16x512]x[512xMpad]. Phase 2: per 32-src chunk,
// owner wave resolves serially in regs (fp32), broadcasts res to LDS in
// A-frag layout, one barrier, everyone rank-32 MFMA-updates later tiles.
// ============================================================
template <int NTW>
__global__ __launch_bounds__(NT)
void net3_kernel(const float* __restrict__ x,
                 const unsigned short* __restrict__ ew2,
                 const float* __restrict__ tri,
                 const int* __restrict__ hdr,
                 const int* __restrict__ ocol,
                 const float* __restrict__ biasc,
                 float* __restrict__ out) {
    const int Mc = hdr[0];  (void)Mc;
    const int ntw = hdr[2], nch = hdr[3], tpm = hdr[4];
    if (NTW == 12) { if (ntw > 12) return; }
    else           { if (ntw <= 12) return; }

    __shared__ __align__(16) unsigned short xa[16 * 64 * 8];      // 16 KB A-frags of x
    __shared__ __align__(16) unsigned short res_lds[2][16 * RS];  // 2x1280 B

    const int t = threadIdx.x, lane = t & 63, w = t >> 6;
    const int l15 = lane & 15, q = lane >> 4;
    const int r0 = blockIdx.x * ROWS;

    // ---- stage x as bf16 A-fragments ----
    for (int p = t; p < 16 * 64; p += NT) {
        const int kb = p >> 6, ln = p & 63;
        const int m = ln & 15, k0 = kb * 32 + ((ln >> 4) << 3);
        const float4 f0 = *(const float4*)&x[(size_t)(r0 + m) * IN_DIM + k0];
        const float4 f1 = *(const float4*)&x[(size_t)(r0 + m) * IN_DIM + k0 + 4];
        unsigned short v[8] = {f2bf(f0.x), f2bf(f0.y), f2bf(f0.z), f2bf(f0.w),
                               f2bf(f1.x), f2bf(f1.y), f2bf(f1.z), f2bf(f1.w)};
        *(uint4*)&xa[p * 8] = *(uint4*)v;
    }
    __syncthreads();

    ffrag acc[NTW];
#pragma unroll
    for (int tt = 0; tt < NTW; ++tt) acc[tt] = (ffrag)0.f;

    const int gt0 = w * ntw;
    const unsigned short* ewp = ew2 + ((size_t)gt0 * 64 + lane) * 8;
    const size_t kstride = (size_t)tpm * 512;   // elems per k-step row

    // ---- phase 1: 16 K-steps ----
    for (int kb = 0; kb < 16; ++kb) {
        const bfrag a = *(const bfrag*)&xa[(kb * 64 + lane) * 8];
        const unsigned short* bp = ewp + (size_t)kb * kstride;
#pragma unroll
        for (int tt = 0; tt < NTW; ++tt) {
            if (tt < ntw) {
                const bfrag b = *(const bfrag*)&bp[tt * 512];
                acc[tt] = __builtin_amdgcn_mfma_f32_16x16x32_bf16(a, b, acc[tt], 0, 0, 0);
            }
        }
    }

    // per-lane bias for owner phase (col = (gt0+tt)*16 + l15)
    float biasr[NTW];
#pragma unroll
    for (int tt = 0; tt < NTW; ++tt)
        biasr[tt] = (tt < ntw) ? biasc[(gt0 + tt) * 16 + l15] : 0.f;

    // ---- phase 2: sequential chunks ----
    int pr = 0;
    for (int j = 0; j < nch; ++j) {
        const int ow = (2 * j) / ntw;          // uniform; ntw even -> no straddle
        if (w == ow) {
            const int lt = 2 * j - ow * ntw;
            ffrag a0 = (ffrag)0.f, a1 = (ffrag)0.f;
            float b0 = 0.f, b1 = 0.f;
#pragma unroll
            for (int tt = 0; tt < NTW; ++tt) {
                if (tt == lt)     { a0 = acc[tt]; b0 = biasr[tt]; }
                if (tt == lt + 1) { a1 = acc[tt]; b1 = biasr[tt]; }
            }
            const float* trij = tri + (size_t)j * 1024;
#pragma unroll
            for (int c = 0; c < 32; ++c) {
                ffrag& ac = (c < 16) ? a0 : a1;
                const float bv = (c < 16) ? b0 : b1;
                float rs[4];
#pragma unroll
                for (int r = 0; r < 4; ++r) {
                    const float s = __fdividef(1.f, 1.f + __expf(-ac[r]));
                    rs[r] = s + bv;
                }
                float br[4];
#pragma unroll
                for (int r = 0; r < 4; ++r)
                    br[r] = __shfl(rs[r], (lane & 48) | (c & 15), 64);
                // in-chunk triangle (tri already zero for cl <= c)
                const float w0 = trij[c * 32 + l15];
                const float w1 = trij[c * 32 + 16 + l15];
#pragma unroll
                for (int r = 0; r < 4; ++r) {
                    a0[r] = fmaf(br[r], w0, a0[r]);
                    a1[r] = fmaf(br[r], w1, a1[r]);
                }
                // res -> LDS (A-frag source), output store
                const int oc = ocol[j * 32 + c];
                if (l15 == (c & 15)) {
#pragma unroll
                    for (int r = 0; r < 4; ++r)
                        res_lds[pr][(4 * q + r) * RS + c] = f2bf(rs[r]);
                    if (oc >= 0) {
#pragma unroll
                        for (int r = 0; r < 4; ++r)
                            out[(size_t)(r0 + 4 * q + r) * OUT_DIM + oc] = rs[r];
                    }
                }
            }
#pragma unroll
            for (int tt = 0; tt < NTW; ++tt) {
                if (tt == lt)     acc[tt] = a0;
                if (tt == lt + 1) acc[tt] = a1;
            }
        }
        __syncthreads();
        // rank-32 MFMA update of all strictly-later tiles
        const bfrag af = *(const bfrag*)&res_lds[pr][l15 * RS + q * 8];
        const unsigned short* bp = ewp + (size_t)(16 + j) * kstride;
#pragma unroll
        for (int tt = 0; tt < NTW; ++tt) {
            if (tt < ntw && (gt0 + tt) >= 2 * (j + 1)) {
                const bfrag b = *(const bfrag*)&bp[tt * 512];
                acc[tt] = __builtin_amdgcn_mfma_f32_16x16x32_bf16(af, b, acc[tt], 0, 0, 0);
            }
        }
        pr ^= 1;
    }
}

// ============================================================
// Fallback (ws too small): round-1 monolithic fp32 kernel.
// ============================================================
__global__ __launch_bounds__(NT, 4)
void net_v1_kernel(const float* __restrict__ x,
                   const float* __restrict__ wsrc,
                   const int* __restrict__ conn,
                   const float* __restrict__ bias,
                   const int* __restrict__ exist,
                   float* __restrict__ out) {
    __shared__ float xs[ROWS * XPAD];
    __shared__ float res_s[2][ROWS];
    float* bias_s  = xs;
    float* exist_s = xs + N_MID;
    const int t = threadIdx.x, rg = t & 3, cg = t >> 2;
    const int r0 = blockIdx.x * ROWS;
    const int c0 = cg * 20;
    {
        const float4* xg = (const float4*)(x + (size_t)r0 * IN_DIM);
        for (int idx = t; idx < ROWS * IN_DIM / 4; idx += NT) {
            const int r = idx >> 7, jj = idx & 127;
            *(float4*)&xs[r * XPAD + jj * 4] = xg[idx];
        }
    }
    __syncthreads();
    float acc[4][20];
#pragma unroll
    for (int a = 0; a < 4; ++a)
#pragma unroll
        for (int k = 0; k < 20; ++k) acc[a][k] = 0.f;
    for (int j = 0; j < IN_DIM; ++j) {
        const size_t woff = (size_t)j * N_MID + c0;
        const float xv0 = xs[rg * XPAD + j];
        const float xv1 = xs[(rg + 4) * XPAD + j];
        const float xv2 = xs[(rg + 8) * XPAD + j];
        const float xv3 = xs[(rg + 12) * XPAD + j];
#pragma unroll
        for (int qq = 0; qq < 5; ++qq) {
            float4 w4 = *(const float4*)(wsrc + woff + qq * 4);
            const int4 c4 = *(const int4*)(conn + woff + qq * 4);
            w4.x *= (float)c4.x; w4.y *= (float)c4.y;
            w4.z *= (float)c4.z; w4.w *= (float)c4.w;
            const float wq[4] = {w4.x, w4.y, w4.z, w4.w};
#pragma unroll
            for (int u = 0; u < 4; ++u) {
                const int k = qq * 4 + u;
                acc[0][k] = fmaf(xv0, wq[u], acc[0][k]);
                acc[1][k] = fmaf(xv1, wq[u], acc[1][k]);
                acc[2][k] = fmaf(xv2, wq[u], acc[2][k]);
                acc[3][k] = fmaf(xv3, wq[u], acc[3][k]);
            }
        }
    }
    __syncthreads();
    for (int idx = t; idx < N_MID; idx += NT) {
        bias_s[idx]  = bias[idx];
        exist_s[idx] = (float)exist[idx];
    }
    __syncthreads();
    int p = 0;
    for (int bb = 0; bb < 64; ++bb) {
#pragma unroll
        for (int kk = 0; kk < 20; ++kk) {
            const int i = bb * 20 + kk;
            const float e = exist_s[i];
            if (e != 0.f) {
                if (cg == bb) {
                    const float bv = bias_s[i];
#pragma unroll
                    for (int a = 0; a < 4; ++a) {
                        const float v = acc[a][kk];
                        const float s = __fdividef(1.f, 1.f + __expf(-v));
                        const float res = (s + bv) * e;
                        res_s[p][rg + 4 * a] = res;
                        if (i >= N_MID - OUT_DIM)
                            out[(size_t)(r0 + rg + 4 * a) * OUT_DIM + (i - (N_MID - OUT_DIM))] = res;
                    }
                }
                __syncthreads();
                const float rv0 = res_s[p][rg];
                const float rv1 = res_s[p][rg + 4];
                const float rv2 = res_s[p][rg + 8];
                const float rv3 = res_s[p][rg + 12];
                const size_t woff = (size_t)(IN_DIM + i) * N_MID + c0;
                if (cg > bb) {
#pragma unroll
                    for (int qq = 0; qq < 5; ++qq) {
                        float4 w4 = *(const float4*)(wsrc + woff + qq * 4);
                        const int4 c4 = *(const int4*)(conn + woff + qq * 4);
                        w4.x *= (float)c4.x; w4.y *= (float)c4.y;
                        w4.z *= (float)c4.z; w4.w *= (float)c4.w;
                        const float wq[4] = {w4.x, w4.y, w4.z, w4.w};
#pragma unroll
                        for (int u = 0; u < 4; ++u) {
                            const int k = qq * 4 + u;
                            acc[0][k] = fmaf(rv0, wq[u], acc[0][k]);
                            acc[1][k] = fmaf(rv1, wq[u], acc[1][k]);
                            acc[2][k] = fmaf(rv2, wq[u], acc[2][k]);
                            acc[3][k] = fmaf(rv3, wq[u], acc[3][k]);
                        }
                    }
                } else if (cg == bb) {
#pragma unroll
                    for (int k = kk + 1; k < 20; ++k) {
                        float ww = wsrc[woff + k] * (float)conn[woff + k];
                        acc[0][k] = fmaf(rv0, ww, acc[0][k]);
                        acc[1][k] = fmaf(rv1, ww, acc[1][k]);
                        acc[2][k] = fmaf(rv2, ww, acc[2][k]);
                        acc[3][k] = fmaf(rv3, ww, acc[3][k]);
                    }
                }
                p ^= 1;
            }
        }
    }
}

extern "C" void kernel_launch(void* const* d_in, const int* in_sizes, int n_in,
                              void* d_out, int out_size, void* d_ws, size_t ws_size,
                              hipStream_t stream) {
    const float* x      = (const float*)d_in[0];
    const float* weight = (const float*)d_in[1];
    const float* bias   = (const float*)d_in[2];
    const int*   conn   = (const int*)d_in[3];
    const int*   exist  = (const int*)d_in[4];
    float*       out    = (float*)d_out;

    if (ws_size >= WS_NEED) {
        char* ws = (char*)d_ws;
        unsigned short* ew2  = (unsigned short*)ws;
        float*          tri  = (float*)(ws + TRI_OFF);
        int*            hdr  = (int*)(ws + HDR_OFF);
        int*            cmap = (int*)(ws + CMAP_OFF);
        int*            ocol = (int*)(ws + OCOL_OFF);
        float*          bsc  = (float*)(ws + BIASC_OFF);

        build_maps_kernel<<<1, 64, 0, stream>>>(exist, bias, hdr, cmap, ocol, bsc);
        {
            const int total = KST_MAX * TPM_MAX * 64;        // 286,720 threads
            gather2_kernel<<<(total + NT - 1) / NT, NT, 0, stream>>>(weight, conn, hdr, cmap, ew2);
        }
        gather_tri_kernel<<<(NCH_MAX * 1024 + NT - 1) / NT, NT, 0, stream>>>(weight, conn, hdr, cmap, tri);
        net3_kernel<12><<<BATCH / ROWS, NT, 0, stream>>>(x, ew2, tri, hdr, ocol, bsc, out);
        net3_kernel<20><<<BATCH / ROWS, NT, 0, stream>>>(x, ew2, tri, hdr, ocol, bsc, out);
    } else {
        net_v1_kernel<<<BATCH / ROWS, NT, 0, stream>>>(x, weight, conn, bias, exist, out);
    }
}

// Round 4
// 843.354 us; speedup vs baseline: 1.4914x; 1.4914x over previous
//
#include <hip/hip_runtime.h>

#define IN_DIM   512
#define OUT_DIM  256
#define N_MID    1280
#define N_NODES  1792
#define BATCH    16384
#define NT       256
#define XPAD     520      // fallback kernel x stride

// net4 geometry: 256 blocks x 1024 threads, 64 rows/block, 16 waves.
// TPW col-tiles (16 cols each) per wave, all 4 row-groups per wave.
// Mpad = TPW*256: TPW=3 -> 768, TPW=4 -> 1024. Mc>1024 -> net_v1 fallback.

// ---- workspace layout (max geometry: tpm=64, ksteps=48, nch=32) ----
#define EW2_ELEMS ((size_t)48 * 64 * 64 * 8)               // bf16 elems = 1,572,864
#define EW2_BYTES (EW2_ELEMS * 2)                          // 3,145,728
#define TRI_OFF   EW2_BYTES
#define TRI_BYTES ((size_t)32 * 1024 * 4)                  // 131,072
#define HDR_OFF   (TRI_OFF + TRI_BYTES)
#define CMAP_OFF  (HDR_OFF + 32)
#define OCOL_OFF  (CMAP_OFF + N_MID * 4)
#define BIASC_OFF (OCOL_OFF + N_MID * 4)
#define WS_NEED   (BIASC_OFF + N_MID * 4)

typedef __attribute__((ext_vector_type(8))) short  bfrag;
typedef __attribute__((ext_vector_type(4))) float  ffrag;

__device__ __forceinline__ unsigned short f2bf(float f) {
    unsigned int u = __float_as_uint(f);
    u += 0x7FFFu + ((u >> 16) & 1u);       // RNE
    return (unsigned short)(u >> 16);
}

// ============================================================
// Setup A: compact existing columns (1 wave).
// hdr = {Mc, Mpad, unused, nch=Mpad/32, tpm=Mpad/16}
// ============================================================
__global__ void build_maps_kernel(const int* __restrict__ exist,
                                  const float* __restrict__ bias,
                                  int* __restrict__ hdr,
                                  int* __restrict__ cmap,
                                  int* __restrict__ ocol,
                                  float* __restrict__ biasc) {
    const int lane = threadIdx.x;   // 64
    int base = 0;
    for (int r = 0; r < N_MID / 64; ++r) {
        const int i = r * 64 + lane;
        const int e = exist[i];
        const unsigned long long m  = __ballot(e != 0);
        const unsigned long long lt = (lane == 0) ? 0ull : (~0ull >> (64 - lane));
        const int pos = base + __popcll(m & lt);
        if (e) {
            cmap[pos]  = i;
            ocol[pos]  = (i >= N_MID - OUT_DIM) ? (i - (N_MID - OUT_DIM)) : -1;
            biasc[pos] = bias[i];
        }
        base += __popcll(m);
    }
    for (int idx = base + lane; idx < N_MID; idx += 64) {
        cmap[idx] = 0; ocol[idx] = -1; biasc[idx] = 0.f;
    }
    if (lane == 0) {
        const int Mc = base;
        int Mpad;
        if (Mc <= 768) Mpad = 768;
        else if (Mc <= 1024) Mpad = 1024;
        else Mpad = (Mc + 127) & ~127;     // v1 fallback territory
        hdr[0] = Mc; hdr[1] = Mpad; hdr[2] = 0;
        hdr[3] = Mpad / 32; hdr[4] = Mpad / 16;
    }
}

// ============================================================
// Setup B: gather eff_w -> bf16 MFMA B-fragment-major.
// ew2[((kstep*tpm + gt)*64 + lane)*8 + jj] = W[s][c]
//   s = kstep*32 + (lane>>4)*8 + jj, c = gt*16 + (lane&15)
// kstep<16: input rows; kstep>=16: compacted source s2=s-512, zero unless
// s2<c, both <Mc, different 32-chunk (same-chunk handled by tri).
// ============================================================
__global__ __launch_bounds__(NT)
void gather2_kernel(const float* __restrict__ w, const int* __restrict__ conn,
                    const int* __restrict__ hdr, const int* __restrict__ cmap,
                    unsigned short* __restrict__ ew2) {
    const int Mc = hdr[0], nch = hdr[3], tpm = hdr[4];
    if (tpm > 64) return;                      // v1 fallback case
    const int tid  = blockIdx.x * NT + threadIdx.x;
    const int lane = tid & 63;
    const int gl   = tid >> 6;
    const int gt   = gl % tpm;
    const int kstep = gl / tpm;
    if (kstep >= 16 + nch) return;
    const int c  = gt * 16 + (lane & 15);
    const int k0 = kstep * 32 + ((lane >> 4) << 3);
    unsigned short v[8];
#pragma unroll
    for (int jj = 0; jj < 8; ++jj) {
        const int s = k0 + jj;
        float val = 0.f;
        if (c < Mc) {
            const int cc = cmap[c];
            if (s < IN_DIM) {
                const size_t o = (size_t)s * N_MID + cc;
                val = w[o] * (float)conn[o];
            } else {
                const int s2 = s - IN_DIM;
                if (s2 < Mc && s2 < c && (s2 >> 5) != (c >> 5)) {
                    const size_t o = (size_t)(IN_DIM + cmap[s2]) * N_MID + cc;
                    val = w[o] * (float)conn[o];
                }
            }
        }
        v[jj] = f2bf(val);
    }
    *(uint4*)&ew2[((size_t)(kstep * tpm + gt) * 64 + lane) * 8] = *(uint4*)v;
}

// ============================================================
// Setup C: in-chunk triangle, fp32. tri[j][sl][cl] nonzero iff sl<cl && col<Mc.
// (sl<cl<Mc guarantees cmap[s] valid.)
// ============================================================
__global__ __launch_bounds__(NT)
void gather_tri_kernel(const float* __restrict__ w, const int* __restrict__ conn,
                       const int* __restrict__ hdr, const int* __restrict__ cmap,
                       float* __restrict__ tri) {
    const int Mc = hdr[0], nch = hdr[3];
    const int idx = blockIdx.x * NT + threadIdx.x;   // < 32*1024
    const int j  = idx >> 10;
    if (j >= nch) return;
    const int sl = (idx >> 5) & 31;
    const int cl = idx & 31;
    const int s = j * 32 + sl, c = j * 32 + cl;
    float v = 0.f;
    if (sl < cl && c < Mc) {
        const size_t o = (size_t)(IN_DIM + cmap[s]) * N_MID + cmap[c];
        v = w[o] * (float)conn[o];
    }
    tri[idx] = v;
}

// ============================================================
// Main kernel (net4): 1 block/CU, 16 waves, 64 rows.
// Wave w owns tiles g0..g0+TPW-1 (x4 row-groups). Per chunk j (2 tiles):
//   1) all waves apply res_{j-1} MFMA to unresolved live tiles
//   2) owning wave(s) stage chunk tiles C-layout -> stage[row][col]
//   3) barrier; resolver wave (lane=row) serial-resolves 32 nodes in regs
//      (tri from LDS, prefetched 1 chunk ahead by helper wave), writes res
//      bf16 to LDS + out stores; barrier.
// ============================================================
template <int TPW>
__global__ __launch_bounds__(1024)
void net4_kernel(const float* __restrict__ x,
                 const unsigned short* __restrict__ ew2,
                 const float* __restrict__ tri_g,
                 const int* __restrict__ hdr,
                 const int* __restrict__ ocol,
                 const float* __restrict__ biasc,
                 float* __restrict__ out) {
    if (hdr[1] != TPW * 256) return;
    const int Mc  = hdr[0];
    const int tpm = hdr[4];                    // TPW*16
    const int nch = TPW * 8;

    __shared__ __align__(16) unsigned short xa[64 * 520];       // 66,560 B
    __shared__ float stage[64 * 33];                             //  8,448 B
    __shared__ __align__(16) unsigned short res_lds[2][64 * 40]; // 10,240 B
    __shared__ __align__(16) float tri_lds[2][1024];             //  8,192 B
    __shared__ float bias_lds[1024];                             //  4,096 B
    __shared__ int   ocol_lds[1024];                             //  4,096 B

    const int t = threadIdx.x, lane = t & 63, w = t >> 6;
    const int l15 = lane & 15, q = lane >> 4;
    const int r0 = blockIdx.x * 64;
    const int g0 = w * TPW;

    // ---- stage bias/ocol + tri chunk 0 + x->bf16 A-layout ----
    for (int i = t; i < TPW * 256; i += 1024) {
        bias_lds[i] = biasc[i];
        ocol_lds[i] = ocol[i];
    }
    if (w == 15) {
        const float4* src = (const float4*)tri_g;
#pragma unroll
        for (int u = 0; u < 4; ++u) {
            const float4 v = src[lane + 64 * u];
            *(float4*)&tri_lds[0][(lane + 64 * u) * 4] = v;
        }
    }
    {
        const float4* xg = (const float4*)(x + (size_t)r0 * IN_DIM);
        for (int i = t; i < 64 * 128; i += 1024) {
            const int row = i >> 7, k4 = i & 127;
            const float4 f = xg[i];
            unsigned short vv[4] = {f2bf(f.x), f2bf(f.y), f2bf(f.z), f2bf(f.w)};
            *(uint2*)&xa[row * 520 + k4 * 4] = *(uint2*)vv;
        }
    }
    __syncthreads();

    ffrag acc[TPW][4];
#pragma unroll
    for (int tt = 0; tt < TPW; ++tt)
#pragma unroll
        for (int rr = 0; rr < 4; ++rr) acc[tt][rr] = (ffrag)0.f;

    // ---- phase 1: input GEMM, 16 k-steps ----
    for (int kb = 0; kb < 16; ++kb) {
        bfrag a[4];
#pragma unroll
        for (int rr = 0; rr < 4; ++rr)
            a[rr] = *(const bfrag*)&xa[(rr * 16 + l15) * 520 + kb * 32 + q * 8];
#pragma unroll
        for (int tt = 0; tt < TPW; ++tt) {
            if ((g0 + tt) * 16 < Mc) {
                const bfrag b = *(const bfrag*)&ew2[((size_t)(kb * tpm + g0 + tt) * 64 + lane) * 8];
#pragma unroll
                for (int rr = 0; rr < 4; ++rr)
                    acc[tt][rr] = __builtin_amdgcn_mfma_f32_16x16x32_bf16(a[rr], b, acc[tt][rr], 0, 0, 0);
            }
        }
    }

    // ---- phase 2: sequential chunks ----
    for (int j = 0; j < nch; ++j) {
        const int cbase = 32 * j;
        if (cbase >= Mc) break;                      // uniform

        if (j > 0) {                                 // apply res_{j-1}
            const int pr = (j - 1) & 1;
            bfrag a[4];
#pragma unroll
            for (int rr = 0; rr < 4; ++rr)
                a[rr] = *(const bfrag*)&res_lds[pr][(rr * 16 + l15) * 40 + q * 8];
#pragma unroll
            for (int tt = 0; tt < TPW; ++tt) {
                const int col0 = (g0 + tt) * 16;
                if (col0 >= cbase && col0 < Mc) {
                    const bfrag b = *(const bfrag*)&ew2[((size_t)((15 + j) * tpm + g0 + tt) * 64 + lane) * 8];
#pragma unroll
                    for (int rr = 0; rr < 4; ++rr)
                        acc[tt][rr] = __builtin_amdgcn_mfma_f32_16x16x32_bf16(a[rr], b, acc[tt][rr], 0, 0, 0);
                }
            }
        }

        // stage chunk tiles (C-layout -> [row][col])
#pragma unroll
        for (int tt = 0; tt < TPW; ++tt) {
            const int g = g0 + tt;
            if (g == 2 * j || g == 2 * j + 1) {
                const int half = (g & 1) ? 16 : 0;
#pragma unroll
                for (int rr = 0; rr < 4; ++rr)
#pragma unroll
                    for (int r = 0; r < 4; ++r)
                        stage[(rr * 16 + 4 * q + r) * 33 + half + l15] = acc[tt][rr][r];
            }
        }
        __syncthreads();                             // A

        const int rsv = j & 15;
        if (w == rsv) {
            // transposed resolve: lane = batch row, 32 node values in regs
            float reg[32];
#pragma unroll
            for (int c = 0; c < 32; ++c) reg[c] = stage[lane * 33 + c];
            const float* trij = tri_lds[j & 1];
            unsigned short* resw = &res_lds[j & 1][lane * 40];
#pragma unroll
            for (int c = 0; c < 32; ++c) {
                const float bv = bias_lds[cbase + c];         // wave-uniform LDS
                const float s  = __fdividef(1.f, 1.f + __expf(-reg[c]));
                const float rs = s + bv;
                resw[c] = f2bf(rs);
                const int oc = ocol_lds[cbase + c];           // uniform
                if (oc >= 0)
                    out[(size_t)(r0 + lane) * OUT_DIM + oc] = rs;
#pragma unroll
                for (int k = c + 1; k < 32; ++k)              // off-chain bulk
                    reg[k] = fmaf(rs, trij[c * 32 + k], reg[k]);
            }
        } else if (w == ((rsv + 8) & 15)) {
            // prefetch tri for chunk j+1 (overlapped with resolve)
            const int jn = j + 1;
            if (jn < nch && 32 * jn < Mc) {
                const float4* src = (const float4*)(tri_g + (size_t)jn * 1024);
#pragma unroll
                for (int u = 0; u < 4; ++u) {
                    const float4 v = src[lane + 64 * u];
                    *(float4*)&tri_lds[jn & 1][(lane + 64 * u) * 4] = v;
                }
            }
        }
        __syncthreads();                             // B
    }
}

// ============================================================
// Fallback (Mc > 1024 or tiny ws): round-1 monolithic fp32 kernel.
// ============================================================
__global__ __launch_bounds__(NT, 4)
void net_v1_kernel(const float* __restrict__ x,
                   const float* __restrict__ wsrc,
                   const int* __restrict__ conn,
                   const float* __restrict__ bias,
                   const int* __restrict__ exist,
                   const int* __restrict__ hdr,   // null = always run
                   float* __restrict__ out) {
    if (hdr && hdr[1] <= 1024) return;
    __shared__ float xs[16 * XPAD];
    __shared__ float res_s[2][16];
    float* bias_s  = xs;
    float* exist_s = xs + N_MID;
    const int t = threadIdx.x, rg = t & 3, cg = t >> 2;
    const int r0 = blockIdx.x * 16;
    const int c0 = cg * 20;
    {
        const float4* xg = (const float4*)(x + (size_t)r0 * IN_DIM);
        for (int idx = t; idx < 16 * IN_DIM / 4; idx += NT) {
            const int r = idx >> 7, jj = idx & 127;
            *(float4*)&xs[r * XPAD + jj * 4] = xg[idx];
        }
    }
    __syncthreads();
    float acc[4][20];
#pragma unroll
    for (int a = 0; a < 4; ++a)
#pragma unroll
        for (int k = 0; k < 20; ++k) acc[a][k] = 0.f;
    for (int j = 0; j < IN_DIM; ++j) {
        const size_t woff = (size_t)j * N_MID + c0;
        const float xv0 = xs[rg * XPAD + j];
        const float xv1 = xs[(rg + 4) * XPAD + j];
        const float xv2 = xs[(rg + 8) * XPAD + j];
        const float xv3 = xs[(rg + 12) * XPAD + j];
#pragma unroll
        for (int qq = 0; qq < 5; ++qq) {
            float4 w4 = *(const float4*)(wsrc + woff + qq * 4);
            const int4 c4 = *(const int4*)(conn + woff + qq * 4);
            w4.x *= (float)c4.x; w4.y *= (float)c4.y;
            w4.z *= (float)c4.z; w4.w *= (float)c4.w;
            const float wq[4] = {w4.x, w4.y, w4.z, w4.w};
#pragma unroll
            for (int u = 0; u < 4; ++u) {
                const int k = qq * 4 + u;
                acc[0][k] = fmaf(xv0, wq[u], acc[0][k]);
                acc[1][k] = fmaf(xv1, wq[u], acc[1][k]);
                acc[2][k] = fmaf(xv2, wq[u], acc[2][k]);
                acc[3][k] = fmaf(xv3, wq[u], acc[3][k]);
            }
        }
    }
    __syncthreads();
    for (int idx = t; idx < N_MID; idx += NT) {
        bias_s[idx]  = bias[idx];
        exist_s[idx] = (float)exist[idx];
    }
    __syncthreads();
    int p = 0;
    for (int bb = 0; bb < 64; ++bb) {
#pragma unroll
        for (int kk = 0; kk < 20; ++kk) {
            const int i = bb * 20 + kk;
            const float e = exist_s[i];
            if (e != 0.f) {
                if (cg == bb) {
                    const float bv = bias_s[i];
#pragma unroll
                    for (int a = 0; a < 4; ++a) {
                        const float v = acc[a][kk];
                        const float s = __fdividef(1.f, 1.f + __expf(-v));
                        const float res = (s + bv) * e;
                        res_s[p][rg + 4 * a] = res;
                        if (i >= N_MID - OUT_DIM)
                            out[(size_t)(r0 + rg + 4 * a) * OUT_DIM + (i - (N_MID - OUT_DIM))] = res;
                    }
                }
                __syncthreads();
                const float rv0 = res_s[p][rg];
                const float rv1 = res_s[p][rg + 4];
                const float rv2 = res_s[p][rg + 8];
                const float rv3 = res_s[p][rg + 12];
                const size_t woff = (size_t)(IN_DIM + i) * N_MID + c0;
                if (cg > bb) {
#pragma unroll
                    for (int qq = 0; qq < 5; ++qq) {
                        float4 w4 = *(const float4*)(wsrc + woff + qq * 4);
                        const int4 c4 = *(const int4*)(conn + woff + qq * 4);
                        w4.x *= (float)c4.x; w4.y *= (float)c4.y;
                        w4.z *= (float)c4.z; w4.w *= (float)c4.w;
                        const float wq[4] = {w4.x, w4.y, w4.z, w4.w};
#pragma unroll
                        for (int u = 0; u < 4; ++u) {
                            const int k = qq * 4 + u;
                            acc[0][k] = fmaf(rv0, wq[u], acc[0][k]);
                            acc[1][k] = fmaf(rv1, wq[u], acc[1][k]);
                            acc[2][k] = fmaf(rv2, wq[u], acc[2][k]);
                            acc[3][k] = fmaf(rv3, wq[u], acc[3][k]);
                        }
                    }
                } else if (cg == bb) {
#pragma unroll
                    for (int k = kk + 1; k < 20; ++k) {
                        float ww = wsrc[woff + k] * (float)conn[woff + k];
                        acc[0][k] = fmaf(rv0, ww, acc[0][k]);
                        acc[1][k] = fmaf(rv1, ww, acc[1][k]);
                        acc[2][k] = fmaf(rv2, ww, acc[2][k]);
                        acc[3][k] = fmaf(rv3, ww, acc[3][k]);
                    }
                }
                p ^= 1;
            }
        }
    }
}

extern "C" void kernel_launch(void* const* d_in, const int* in_sizes, int n_in,
                              void* d_out, int out_size, void* d_ws, size_t ws_size,
                              hipStream_t stream) {
    const float* x      = (const float*)d_in[0];
    const float* weight = (const float*)d_in[1];
    const float* bias   = (const float*)d_in[2];
    const int*   conn   = (const int*)d_in[3];
    const int*   exist  = (const int*)d_in[4];
    float*       out    = (float*)d_out;

    if (ws_size >= WS_NEED) {
        char* ws = (char*)d_ws;
        unsigned short* ew2  = (unsigned short*)ws;
        float*          tri  = (float*)(ws + TRI_OFF);
        int*            hdr  = (int*)(ws + HDR_OFF);
        int*            cmap = (int*)(ws + CMAP_OFF);
        int*            ocolp= (int*)(ws + OCOL_OFF);
        float*          bsc  = (float*)(ws + BIASC_OFF);

        build_maps_kernel<<<1, 64, 0, stream>>>(exist, bias, hdr, cmap, ocolp, bsc);
        gather2_kernel<<<768, NT, 0, stream>>>(weight, conn, hdr, cmap, ew2);
        gather_tri_kernel<<<128, NT, 0, stream>>>(weight, conn, hdr, cmap, tri);
        net4_kernel<3><<<BATCH / 64, 1024, 0, stream>>>(x, ew2, tri, hdr, ocolp, bsc, out);
        net4_kernel<4><<<BATCH / 64, 1024, 0, stream>>>(x, ew2, tri, hdr, ocolp, bsc, out);
        net_v1_kernel<<<BATCH / 16, NT, 0, stream>>>(x, weight, conn, bias, exist, hdr, out);
    } else {
        net_v1_kernel<<<BATCH / 16, NT, 0, stream>>>(x, weight, conn, bias, exist, nullptr, out);
    }
}